// Round 2
// baseline (25769.003 us; speedup 1.0000x reference)
//
#include <hip/hip_runtime.h>
#include <hip/hip_bf16.h>

// GridNetBlock round-1: dtype-robust full implementation.
// Detects input dtype (bf16 vs fp32) on device, converts all params to an
// fp32 arena (exact either way), computes in fp32, stores output in the
// detected dtype. B=4 T=512 NF=65 C=128 NH=4 E=8 H=256 DOWN=4 L=100 VD=32.
//
// ws layout (bytes):
//  A [0,68.2M):        hc[16.8M]+yf[33.5M]  ->  ln1y -> Vh -> ph
//  B [68.2M,136.3M):   intra -> av
//  C [136.3M,204.5M):  x32 -> inter
//  DE[204.5M,238.6M):  yr[33.5M] -> Qh[17M]+Kh[17M]
//  WT[238.6M,243.3M):  fp32 transposed LSTM weights
//  AR[243.3M,245.5M):  fp32 arena (all other params)
//  FLAG @245.53M

typedef unsigned short u16;
typedef unsigned int u32;

#define OFF_A    0ULL
#define OFF_B    68157440ULL
#define OFF_C    136314880ULL
#define OFF_DE   204472320ULL
#define OFF_WT   238551040ULL
#define OFF_AR   243269632ULL
#define OFF_FLAG 245529088ULL

__device__ __forceinline__ float b2f(u16 u) {
  union { u32 i; float f; } v; v.i = ((u32)u) << 16; return v.f;
}
__device__ __forceinline__ float sigf(float x) { return 1.f / (1.f + __expf(-x)); }
__device__ __forceinline__ float tanh_(float x) {
  float cx = fminf(15.f, fmaxf(-15.f, x));
  float e = __expf(2.f * cx);
  return (e - 1.f) / (e + 1.f);
}
__device__ __forceinline__ void wavered2(float& s, float& q) {
  #pragma unroll
  for (int o = 32; o > 0; o >>= 1) {
    s += __shfl_down(s, o, 64);
    q += __shfl_down(q, o, 64);
  }
}

// ---------------- dtype detection ----------------
// bf16 data: even-index u16s are bf16 values (sane exponents ~[112,143] or 0).
// fp32 data: even-index u16s are mantissa low halves (uniform-ish exponent field).
__global__ void k_detect(const u16* __restrict__ x, int* __restrict__ flag) {
  __shared__ int cnt;
  if (threadIdx.x == 0) cnt = 0;
  __syncthreads();
  int sane = 0;
  for (int i = threadIdx.x; i < 2048; i += 256) {
    u16 u = x[2 * i];
    int e = (u >> 7) & 0xFF;
    if (u == 0 || (e >= 0x70 && e <= 0x8F)) sane++;
  }
  atomicAdd(&cnt, sane);
  __syncthreads();
  if (threadIdx.x == 0) *flag = (cnt < 1024) ? 1 : 0;   // 1 => fp32 inputs
}

// ---------------- convert params to fp32 arena ----------------
#define NCVT 40
struct CvtTab {
  const void* src[NCVT];
  float* dst[NCVT];
  int n[NCVT];
};

__global__ __launch_bounds__(256) void k_cvt(CvtTab tab, const int* __restrict__ flag) {
  bool f32 = (*flag != 0);
  long gid = (long)blockIdx.x * 256 + threadIdx.x;
  long stride = (long)gridDim.x * 256;
  for (int e = 0; e < NCVT; ++e) {
    long n = tab.n[e];
    float* dst = tab.dst[e];
    if (f32) {
      const float* s = (const float*)tab.src[e];
      for (long i = gid; i < n; i += stride) dst[i] = s[i];
    } else {
      const u16* s = (const u16*)tab.src[e];
      for (long i = gid; i < n; i += stride) dst[i] = b2f(s[i]);
    }
  }
}

// ---------------- transpose [R][K] -> fp32 [K][R] ----------------
__global__ void k_transpose(const void* __restrict__ src, float* __restrict__ dst,
                            int R, int K, const int* __restrict__ flag) {
  int e = blockIdx.x * 256 + threadIdx.x;
  if (e >= R * K) return;
  int r = e / K, k = e - r * K;
  float v = (*flag) ? ((const float*)src)[e] : b2f(((const u16*)src)[e]);
  dst[k * R + r] = v;
}

// ---------------- conv(k=s=4) + bias + PReLU + LN(C) ----------------
__global__ __launch_bounds__(256) void k_conv_ln0(
    const float* __restrict__ x32, const float* __restrict__ cw,
    const float* __restrict__ cb, const float* __restrict__ ca,
    const float* __restrict__ g0, const float* __restrict__ b0,
    float* __restrict__ hc) {
  __shared__ float xs[8192];   // [64 freq][128 c]
  __shared__ float hs[2048];   // [16][128]
  __shared__ float mu_[16], ri_[16];
  int n = blockIdx.x, tid = threadIdx.x;
  const float4* xr = (const float4*)(x32 + (size_t)n * 8320);
  for (int e = tid; e < 2048; e += 256) ((float4*)xs)[e] = xr[e];
  __syncthreads();
  int g = tid >> 7, o = tid & 127;
  float a = ca[0];
  float cbv = cb[o];
  float acc[8];
  #pragma unroll
  for (int j = 0; j < 8; ++j) acc[j] = cbv;
  const float4* cw4 = (const float4*)cw;   // [o][c][4m]
  for (int c = 0; c < 128; ++c) {
    float4 w = cw4[o * 128 + c];
    #pragma unroll
    for (int j = 0; j < 8; ++j) {
      int i = 8 * g + j;
      const float* xi = &xs[i * 512 + c];
      acc[j] += w.x * xi[0] + w.y * xi[128] + w.z * xi[256] + w.w * xi[384];
    }
  }
  #pragma unroll
  for (int j = 0; j < 8; ++j) {
    int i = 8 * g + j;
    float v = acc[j];
    v = v >= 0.f ? v : a * v;
    hs[i * 128 + o] = v;
  }
  __syncthreads();
  if (tid < 16) {
    float s = 0.f, q = 0.f;
    for (int c = 0; c < 128; ++c) { float v = hs[tid * 128 + c]; s += v; q += v * v; }
    float mu = s / 128.f;
    mu_[tid] = mu;
    ri_[tid] = rsqrtf(fmaxf(q / 128.f - mu * mu, 0.f) + 1e-5f);
  }
  __syncthreads();
  float gg = g0[o], bb = b0[o];
  #pragma unroll
  for (int j = 0; j < 8; ++j) {
    int i = 8 * g + j;
    hc[((size_t)n * 16 + i) * 128 + o] = (hs[i * 128 + o] - mu_[i]) * ri_[i] * gg + bb;
  }
}

// ---------------- intra BiLSTM over freq (seq len 16) ----------------
__global__ __launch_bounds__(256) void k_intra_lstm(
    const float* __restrict__ hc,
    const float* __restrict__ wiTf, const float* __restrict__ whTf,
    const float* __restrict__ bihf, const float* __restrict__ bhhf,
    const float* __restrict__ wiTr, const float* __restrict__ whTr,
    const float* __restrict__ bihr, const float* __restrict__ bhhr,
    float* __restrict__ yf, float* __restrict__ yr) {
  __shared__ float xt[1024];    // [8][128]
  __shared__ float hsh[2048];   // [8][256]
  __shared__ float csh[2048];
  __shared__ float gbuf[8192];  // [8][1024]
  int tid = threadIdx.x;
  int grp = blockIdx.x & 255, dir = blockIdx.x >> 8;
  int n0 = grp * 8;
  const float4* wi4 = (const float4*)(dir ? wiTr : wiTf);
  const float4* wh4 = (const float4*)(dir ? whTr : whTf);
  const float* bi = dir ? bihr : bihf;
  const float* bh = dir ? bhhr : bhhf;
  float* yo = dir ? yr : yf;
  float bias[4];
  #pragma unroll
  for (int j = 0; j < 4; ++j) bias[j] = bi[4 * tid + j] + bh[4 * tid + j];
  for (int e = tid; e < 2048; e += 256) { hsh[e] = 0.f; csh[e] = 0.f; }
  for (int t = 0; t < 16; ++t) {
    int tt = dir ? 15 - t : t;
    for (int e = tid; e < 1024; e += 256)
      xt[e] = hc[((size_t)(n0 + (e >> 7)) * 16 + tt) * 128 + (e & 127)];
    __syncthreads();
    float acc[4][8];
    #pragma unroll
    for (int j = 0; j < 4; ++j)
      #pragma unroll
      for (int s = 0; s < 8; ++s) acc[j][s] = bias[j];
    for (int k = 0; k < 128; ++k) {
      float4 w = wi4[k * 256 + tid];
      #pragma unroll
      for (int s = 0; s < 8; ++s) {
        float xv = xt[s * 128 + k];
        acc[0][s] += w.x * xv; acc[1][s] += w.y * xv;
        acc[2][s] += w.z * xv; acc[3][s] += w.w * xv;
      }
    }
    for (int k = 0; k < 256; ++k) {
      float4 w = wh4[k * 256 + tid];
      #pragma unroll
      for (int s = 0; s < 8; ++s) {
        float hv = hsh[s * 256 + k];
        acc[0][s] += w.x * hv; acc[1][s] += w.y * hv;
        acc[2][s] += w.z * hv; acc[3][s] += w.w * hv;
      }
    }
    #pragma unroll
    for (int j = 0; j < 4; ++j)
      #pragma unroll
      for (int s = 0; s < 8; ++s)
        gbuf[s * 1024 + 4 * tid + j] = acc[j][s];
    __syncthreads();
    #pragma unroll
    for (int s = 0; s < 8; ++s) {
      float iv = gbuf[s * 1024 + tid];
      float fv = gbuf[s * 1024 + 256 + tid];
      float gv = gbuf[s * 1024 + 512 + tid];
      float ov = gbuf[s * 1024 + 768 + tid];
      float cn = sigf(fv) * csh[s * 256 + tid] + sigf(iv) * tanh_(gv);
      float hn = sigf(ov) * tanh_(cn);
      csh[s * 256 + tid] = cn;
      hsh[s * 256 + tid] = hn;
      yo[((size_t)(n0 + s) * 16 + tt) * 256 + tid] = hn;   // stored at ORIGINAL pos
    }
    __syncthreads();
  }
}

// ---------------- deconv(k=s=4) + bias + pad + residual ----------------
__global__ __launch_bounds__(256) void k_deconv(
    const float* __restrict__ yf, const float* __restrict__ yr,
    const float* __restrict__ dw, const float* __restrict__ db,
    const float* __restrict__ x32, float* __restrict__ intra) {
  __shared__ float hbi[8192];   // [16][512]
  int n = blockIdx.x, tid = threadIdx.x;
  for (int e = tid; e < 8192; e += 256) {
    int i = e >> 9, d = e & 511;
    hbi[e] = d < 256 ? yf[((size_t)n * 16 + i) * 256 + d]
                     : yr[((size_t)n * 16 + i) * 256 + d - 256];
  }
  __syncthreads();
  int op0 = tid, op1 = tid + 256;   // op = o*4 + m
  float acc0[16], acc1[16];
  #pragma unroll
  for (int i = 0; i < 16; ++i) { acc0[i] = 0.f; acc1[i] = 0.f; }
  for (int d = 0; d < 512; d += 2) {
    float w00 = dw[(size_t)d * 512 + op0];
    float w01 = dw[(size_t)d * 512 + op1];
    float w10 = dw[(size_t)(d + 1) * 512 + op0];
    float w11 = dw[(size_t)(d + 1) * 512 + op1];
    #pragma unroll
    for (int i = 0; i < 16; ++i) {
      float2 hv = *(const float2*)&hbi[i * 512 + d];
      acc0[i] += hv.x * w00 + hv.y * w10;
      acc1[i] += hv.x * w01 + hv.y * w11;
    }
  }
  int o0 = op0 >> 2, m0 = op0 & 3, o1 = op1 >> 2, m1 = op1 & 3;
  float db0 = db[o0], db1 = db[o1];
  #pragma unroll
  for (int i = 0; i < 16; ++i) {
    size_t i0 = ((size_t)n * 65 + i * 4 + m0) * 128 + o0;
    size_t i1 = ((size_t)n * 65 + i * 4 + m1) * 128 + o1;
    intra[i0] = acc0[i] + db0 + x32[i0];
    intra[i1] = acc1[i] + db1 + x32[i1];
  }
  if (tid < 128) {   // padded freq row 64: zeros + bias + residual
    size_t ip = ((size_t)n * 65 + 64) * 128 + tid;
    intra[ip] = db[tid] + x32[ip];
  }
}

// ---------------- LN over C + transpose to [B*NF][T][C] ----------------
__global__ __launch_bounds__(256) void k_ln1(
    const float* __restrict__ intra, const float* __restrict__ g1,
    const float* __restrict__ b1, float* __restrict__ out) {
  __shared__ float rs[4], rq[4];
  int n = blockIdx.x, tid = threadIdx.x;
  int gr = tid >> 7, o = tid & 127, wid = tid >> 6;
  int b = n >> 9, t = n & 511;
  float gv = g1[o], bv = b1[o];
  for (int f0 = 0; f0 < 65; f0 += 2) {
    int f = f0 + gr;
    bool ok = f < 65;
    float v = 0.f;
    if (ok) v = intra[((size_t)n * 65 + f) * 128 + o];
    float s = v, q = v * v;
    wavered2(s, q);
    if ((tid & 63) == 0) { rs[wid] = s; rq[wid] = q; }
    __syncthreads();
    if (ok) {
      float S = rs[2 * gr] + rs[2 * gr + 1], Q = rq[2 * gr] + rq[2 * gr + 1];
      float mu = S / 128.f;
      float rinv = rsqrtf(fmaxf(Q / 128.f - mu * mu, 0.f) + 1e-5f);
      out[((size_t)(b * 65 + f) * 512 + t) * 128 + o] = (v - mu) * rinv * gv + bv;
    }
    __syncthreads();
  }
}

// ---------------- inter causal LSTM over time + fused Linear + residual ----------------
__global__ __launch_bounds__(256) void k_inter_lstm(
    const float* __restrict__ ln1y,
    const float* __restrict__ wiT, const float* __restrict__ whT,
    const float* __restrict__ bih, const float* __restrict__ bhh,
    const float* __restrict__ lw, const float* __restrict__ lb,
    const float* __restrict__ h0a, const float* __restrict__ c0a,
    const float* __restrict__ intra, float* __restrict__ inter) {
  __shared__ float xt[256];     // [2][128]
  __shared__ float hsh[512];    // [2][256]
  __shared__ float csh[512];
  __shared__ float gbuf[2048];  // [2][1024]
  int tid = threadIdx.x;
  int n0 = blockIdx.x * 2;
  for (int e = tid; e < 512; e += 256) {
    hsh[e] = h0a[(size_t)n0 * 256 + e];
    csh[e] = c0a[(size_t)n0 * 256 + e];
  }
  float bias[4];
  #pragma unroll
  for (int j = 0; j < 4; ++j) bias[j] = bih[4 * tid + j] + bhh[4 * tid + j];
  const float4* wi4 = (const float4*)wiT;
  const float4* wh4 = (const float4*)whT;
  int s_l = tid >> 7, ci = tid & 127;
  int n_l = n0 + s_l;
  int b_l = n_l / 65, f_l = n_l - b_l * 65;
  float linb = lb[ci];
  const float4* lr4 = (const float4*)(lw + (size_t)ci * 256);
  for (int t = 0; t < 512; ++t) {
    xt[tid] = ln1y[(size_t)(n0 + (tid >> 7)) * 65536 + (size_t)t * 128 + (tid & 127)];
    __syncthreads();
    float a0[4], a1[4];
    #pragma unroll
    for (int j = 0; j < 4; ++j) { a0[j] = bias[j]; a1[j] = bias[j]; }
    for (int k = 0; k < 128; ++k) {
      float4 w = wi4[k * 256 + tid];
      float x0 = xt[k], x1 = xt[128 + k];
      a0[0] += w.x * x0; a0[1] += w.y * x0; a0[2] += w.z * x0; a0[3] += w.w * x0;
      a1[0] += w.x * x1; a1[1] += w.y * x1; a1[2] += w.z * x1; a1[3] += w.w * x1;
    }
    for (int k = 0; k < 256; ++k) {
      float4 w = wh4[k * 256 + tid];
      float x0 = hsh[k], x1 = hsh[256 + k];
      a0[0] += w.x * x0; a0[1] += w.y * x0; a0[2] += w.z * x0; a0[3] += w.w * x0;
      a1[0] += w.x * x1; a1[1] += w.y * x1; a1[2] += w.z * x1; a1[3] += w.w * x1;
    }
    #pragma unroll
    for (int j = 0; j < 4; ++j) {
      gbuf[4 * tid + j] = a0[j];
      gbuf[1024 + 4 * tid + j] = a1[j];
    }
    __syncthreads();
    #pragma unroll
    for (int s = 0; s < 2; ++s) {
      float iv = gbuf[s * 1024 + tid];
      float fv = gbuf[s * 1024 + 256 + tid];
      float gv = gbuf[s * 1024 + 512 + tid];
      float ov = gbuf[s * 1024 + 768 + tid];
      float cn = sigf(fv) * csh[s * 256 + tid] + sigf(iv) * tanh_(gv);
      float hn = sigf(ov) * tanh_(cn);
      csh[s * 256 + tid] = cn;
      hsh[s * 256 + tid] = hn;
    }
    __syncthreads();
    float acc = linb;
    const float* hr = &hsh[s_l * 256];
    #pragma unroll
    for (int qq = 0; qq < 64; ++qq) {
      float4 u = lr4[qq];
      int k = qq * 4;
      acc += u.x * hr[k] + u.y * hr[k + 1] + u.z * hr[k + 2] + u.w * hr[k + 3];
    }
    size_t oi = ((size_t)(b_l * 512 + t) * 65 + f_l) * 128 + ci;
    inter[oi] = acc + intra[oi];
  }
}

// ---------------- Q/K/V projections + PReLU (pre-LN) ----------------
__global__ __launch_bounds__(256) void k_qkv(
    const float* __restrict__ inter,
    const float* __restrict__ qw, const float* __restrict__ qb, const float* __restrict__ qa,
    const float* __restrict__ kw, const float* __restrict__ kb, const float* __restrict__ ka,
    const float* __restrict__ vw, const float* __restrict__ vb, const float* __restrict__ va,
    float* __restrict__ Qh, float* __restrict__ Kh, float* __restrict__ Vh) {
  __shared__ float xsl[8320];
  int n = blockIdx.x, tid = threadIdx.x;
  int b = n >> 9, t = n & 511;
  for (int e = tid; e < 8320; e += 256) xsl[e] = inter[(size_t)n * 8320 + e];
  __syncthreads();
  if (tid >= 192) return;
  const float* wrow; float bias, a; float* dst; int dsz;
  if (tid < 32) {
    wrow = qw + (size_t)tid * 128; bias = qb[tid]; a = qa[0];
    dst = Qh + ((size_t)(b * 4 + (tid >> 3)) * 512 + t) * 520 + (tid & 7); dsz = 8;
  } else if (tid < 64) {
    int d = tid - 32;
    wrow = kw + (size_t)d * 128; bias = kb[d]; a = ka[0];
    dst = Kh + ((size_t)(b * 4 + (d >> 3)) * 512 + t) * 520 + (d & 7); dsz = 8;
  } else {
    int d = tid - 64;
    wrow = vw + (size_t)d * 128; bias = vb[d]; a = va[0];
    dst = Vh + ((size_t)(b * 4 + (d >> 5)) * 512 + t) * 2080 + (d & 31); dsz = 32;
  }
  const float4* w4 = (const float4*)wrow;
  for (int f = 0; f < 65; ++f) {
    float acc = bias;
    const float4* xr = (const float4*)&xsl[f * 128];
    #pragma unroll
    for (int kk = 0; kk < 32; ++kk) {
      float4 w = w4[kk], xv = xr[kk];
      acc += w.x * xv.x + w.y * xv.y + w.z * xv.z + w.w * xv.w;
    }
    acc = acc >= 0.f ? acc : a * acc;
    dst[(size_t)f * dsz] = acc;
  }
}

// ---------------- LN over last dim (in-place) ----------------
__global__ __launch_bounds__(256) void k_lnrow(
    float* __restrict__ buf, int len,
    const float* __restrict__ g, const float* __restrict__ b) {
  __shared__ float rs[4], rq[4];
  int row = blockIdx.x, tid = threadIdx.x;
  float* p = buf + (size_t)row * len;
  float s = 0.f, q = 0.f;
  for (int e = tid; e < len; e += 256) { float v = p[e]; s += v; q += v * v; }
  wavered2(s, q);
  if ((tid & 63) == 0) { rs[tid >> 6] = s; rq[tid >> 6] = q; }
  __syncthreads();
  float S = rs[0] + rs[1] + rs[2] + rs[3];
  float Q = rq[0] + rq[1] + rq[2] + rq[3];
  float mu = S / len;
  float rinv = rsqrtf(fmaxf(Q / len - mu * mu, 0.f) + 1e-5f);
  for (int e = tid; e < len; e += 256) {
    float v = p[e];
    p[e] = (v - mu) * rinv * g[e] + b[e];
  }
}

// ---------------- windowed causal attention (100 keys) ----------------
__global__ __launch_bounds__(256) void k_attn(
    const float* __restrict__ Qh, const float* __restrict__ Kh,
    const float* __restrict__ Vh, const void* __restrict__ Kbuf,
    const void* __restrict__ Vbuf, const int* __restrict__ flagp,
    float* __restrict__ av) {
  __shared__ float qrow[520], sc[100], red[2];
  int bid = blockIdx.x, tid = threadIdx.x;
  int bh = bid >> 9, t = bid & 511;
  int f32 = *flagp;
  for (int e = tid; e < 520; e += 256)
    qrow[e] = Qh[((size_t)bh * 512 + t) * 520 + e];
  __syncthreads();
  if (tid < 100) {
    int s = t + tid;
    float acc = 0.f;
    if (s < 99) {
      if (f32) {
        const float* kr = (const float*)Kbuf + ((size_t)bh * 99 + s) * 520;
        for (int e = 0; e < 520; ++e) acc += qrow[e] * kr[e];
      } else {
        const u16* kr = (const u16*)Kbuf + ((size_t)bh * 99 + s) * 520;
        for (int e = 0; e < 520; ++e) acc += qrow[e] * b2f(kr[e]);
      }
    } else {
      const float* kr = Kh + ((size_t)bh * 512 + (s - 99)) * 520;
      for (int e = 0; e < 520; ++e) acc += qrow[e] * kr[e];
    }
    sc[tid] = acc * 0.04385290096535147f;   // 1/sqrt(520)
  }
  __syncthreads();
  if (tid == 0) {
    float m = sc[0];
    for (int k = 1; k < 100; ++k) m = fmaxf(m, sc[k]);
    red[0] = m;
  }
  __syncthreads();
  if (tid < 100) sc[tid] = __expf(sc[tid] - red[0]);
  __syncthreads();
  if (tid == 0) {
    float s = 0.f;
    for (int k = 0; k < 100; ++k) s += sc[k];
    red[1] = 1.f / s;
  }
  __syncthreads();
  float rscale = red[1];
  int b = bh >> 2, nh = bh & 3;
  int kb = t < 99 ? 99 - t : 0;
  for (int o = tid; o < 2080; o += 256) {
    float acc = 0.f;
    if (f32) {
      const float* vb32 = (const float*)Vbuf;
      for (int k = 0; k < kb; ++k)
        acc += sc[k] * vb32[((size_t)bh * 99 + t + k) * 2080 + o];
    } else {
      const u16* vb16 = (const u16*)Vbuf;
      for (int k = 0; k < kb; ++k)
        acc += sc[k] * b2f(vb16[((size_t)bh * 99 + t + k) * 2080 + o]);
    }
    for (int k = kb; k < 100; ++k)
      acc += sc[k] * Vh[((size_t)bh * 512 + (t + k - 99)) * 2080 + o];
    int f = o >> 5, vd = o & 31;
    av[((size_t)(b * 512 + t) * 65 + f) * 128 + nh * 32 + vd] = acc * rscale;
  }
}

// ---------------- P projection + PReLU ----------------
__global__ __launch_bounds__(256) void k_pproj(
    const float* __restrict__ av, const float* __restrict__ pw,
    const float* __restrict__ pb, const float* __restrict__ pa,
    float* __restrict__ ph) {
  __shared__ float avs[8320];
  int n = blockIdx.x, tid = threadIdx.x;
  for (int e = tid; e < 8320; e += 256) avs[e] = av[(size_t)n * 8320 + e];
  __syncthreads();
  int o = tid & 127, g = tid >> 7;
  float a = pa[0], bias = pb[o];
  const float4* w4 = (const float4*)(pw + (size_t)o * 128);
  for (int f = g; f < 65; f += 2) {
    float acc = bias;
    const float4* xr = (const float4*)&avs[f * 128];
    #pragma unroll
    for (int kk = 0; kk < 32; ++kk) {
      float4 w = w4[kk], xv = xr[kk];
      acc += w.x * xv.x + w.y * xv.y + w.z * xv.z + w.w * xv.w;
    }
    acc = acc >= 0.f ? acc : a * acc;
    ph[(size_t)n * 8320 + f * 128 + o] = acc;
  }
}

// ---------------- final LN(8320) + residual -> out (dtype by flag) ----------------
__global__ __launch_bounds__(256) void k_lnfinal(
    const float* __restrict__ ph, const float* __restrict__ plg,
    const float* __restrict__ plb, const float* __restrict__ inter,
    const int* __restrict__ flagp, void* __restrict__ out) {
  __shared__ float rs[4], rq[4];
  int n = blockIdx.x, tid = threadIdx.x;
  int f32 = *flagp;
  const float* p = ph + (size_t)n * 8320;
  float s = 0.f, q = 0.f;
  for (int e = tid; e < 8320; e += 256) { float v = p[e]; s += v; q += v * v; }
  wavered2(s, q);
  if ((tid & 63) == 0) { rs[tid >> 6] = s; rq[tid >> 6] = q; }
  __syncthreads();
  float S = rs[0] + rs[1] + rs[2] + rs[3];
  float Q = rq[0] + rq[1] + rq[2] + rq[3];
  float mu = S / 8320.f;
  float rinv = rsqrtf(fmaxf(Q / 8320.f - mu * mu, 0.f) + 1e-5f);
  for (int e = tid; e < 8320; e += 256) {
    float v = (p[e] - mu) * rinv * plg[e] + plb[e] + inter[(size_t)n * 8320 + e];
    if (f32) ((float*)out)[(size_t)n * 8320 + e] = v;
    else ((__hip_bfloat16*)out)[(size_t)n * 8320 + e] = __float2bfloat16(v);
  }
}

extern "C" void kernel_launch(void* const* d_in, const int* in_sizes, int n_in,
                              void* d_out, int out_size, void* d_ws, size_t ws_size,
                              hipStream_t stream) {
  char* ws = (char*)d_ws;
  float* hc    = (float*)(ws + OFF_A);
  float* yfb   = (float*)(ws + OFF_A + 16777216ULL);
  float* yrb   = (float*)(ws + OFF_DE);
  float* ln1y  = (float*)(ws + OFF_A);
  float* Vh    = (float*)(ws + OFF_A);
  float* phb   = (float*)(ws + OFF_A);
  float* intra = (float*)(ws + OFF_B);
  float* avb   = (float*)(ws + OFF_B);
  float* x32   = (float*)(ws + OFF_C);
  float* inter = (float*)(ws + OFF_C);
  float* Qh    = (float*)(ws + OFF_DE);
  float* Kh    = (float*)(ws + OFF_DE + 17039360ULL);
  float* wT    = (float*)(ws + OFF_WT);
  float* wiTf = wT + 0;        // 131072
  float* whTf = wT + 131072;   // 262144
  float* wiTr = wT + 393216;
  float* whTr = wT + 524288;
  float* wiT2 = wT + 786432;
  float* whT2 = wT + 917504;   // ends 1179648 floats = 4718592 B
  int* flagp = (int*)(ws + OFF_FLAG);

  // ---- fp32 arena ----
  float* ar = (float*)(ws + OFF_AR);
  CvtTab tab;
  int ne = 0;
  auto add = [&](int idx, int n, float*& dst) {
    dst = ar; ar += (n + 3) & ~3;
    tab.src[ne] = d_in[idx]; tab.dst[ne] = dst; tab.n[ne] = n; ne++;
  };
  float *A_convw, *A_convb, *A_conva, *A_ln0g, *A_ln0b;
  float *A_dcw, *A_dcb, *A_ln1g, *A_ln1b;
  float *A_bihf, *A_bhhf, *A_bihr, *A_bhhr, *A_bih2, *A_bhh2;
  float *A_linw, *A_linb;
  float *A_qw, *A_qb, *A_qa, *A_qlg, *A_qlb;
  float *A_kw, *A_kb, *A_ka, *A_klg, *A_klb;
  float *A_vw, *A_vb, *A_va, *A_vlg, *A_vlb;
  float *A_pw, *A_pb, *A_pa, *A_plg, *A_plb;
  float *A_h0, *A_c0, *A_x32;
  add(1, 65536, A_convw);
  add(2, 128, A_convb);
  add(3, 1, A_conva);
  add(4, 128, A_ln0g);
  add(5, 128, A_ln0b);
  add(14, 262144, A_dcw);
  add(15, 128, A_dcb);
  add(16, 128, A_ln1g);
  add(17, 128, A_ln1b);
  add(8, 1024, A_bihf);
  add(9, 1024, A_bhhf);
  add(12, 1024, A_bihr);
  add(13, 1024, A_bhhr);
  add(20, 1024, A_bih2);
  add(21, 1024, A_bhh2);
  add(22, 32768, A_linw);
  add(23, 128, A_linb);
  add(24, 4096, A_qw);
  add(25, 32, A_qb);
  add(26, 1, A_qa);
  add(27, 520, A_qlg);
  add(28, 520, A_qlb);
  add(29, 4096, A_kw);
  add(30, 32, A_kb);
  add(31, 1, A_ka);
  add(32, 520, A_klg);
  add(33, 520, A_klb);
  add(34, 16384, A_vw);
  add(35, 128, A_vb);
  add(36, 1, A_va);
  add(37, 2080, A_vlg);
  add(38, 2080, A_vlb);
  add(39, 16384, A_pw);
  add(40, 128, A_pb);
  add(41, 1, A_pa);
  add(42, 8320, A_plg);
  add(43, 8320, A_plb);
  add(46, 66560, A_h0);
  add(47, 66560, A_c0);
  // x -> x32 (into slot C, not arena)
  tab.src[ne] = d_in[0]; tab.dst[ne] = x32; tab.n[ne] = 17039360; ne++;
  for (; ne < NCVT; ++ne) { tab.src[ne] = d_in[0]; tab.dst[ne] = x32; tab.n[ne] = 0; }

  k_detect<<<1, 256, 0, stream>>>((const u16*)d_in[0], flagp);
  k_cvt<<<2048, 256, 0, stream>>>(tab, flagp);

  k_transpose<<<512, 256, 0, stream>>>(d_in[6], wiTf, 1024, 128, flagp);
  k_transpose<<<1024, 256, 0, stream>>>(d_in[7], whTf, 1024, 256, flagp);
  k_transpose<<<512, 256, 0, stream>>>(d_in[10], wiTr, 1024, 128, flagp);
  k_transpose<<<1024, 256, 0, stream>>>(d_in[11], whTr, 1024, 256, flagp);
  k_transpose<<<512, 256, 0, stream>>>(d_in[18], wiT2, 1024, 128, flagp);
  k_transpose<<<1024, 256, 0, stream>>>(d_in[19], whT2, 1024, 256, flagp);

  k_conv_ln0<<<2048, 256, 0, stream>>>(x32, A_convw, A_convb, A_conva, A_ln0g, A_ln0b, hc);
  k_intra_lstm<<<512, 256, 0, stream>>>(hc, wiTf, whTf, A_bihf, A_bhhf,
                                        wiTr, whTr, A_bihr, A_bhhr, yfb, yrb);
  k_deconv<<<2048, 256, 0, stream>>>(yfb, yrb, A_dcw, A_dcb, x32, intra);
  k_ln1<<<2048, 256, 0, stream>>>(intra, A_ln1g, A_ln1b, ln1y);
  k_inter_lstm<<<130, 256, 0, stream>>>(ln1y, wiT2, whT2, A_bih2, A_bhh2,
                                        A_linw, A_linb, A_h0, A_c0, intra, inter);
  k_qkv<<<2048, 256, 0, stream>>>(inter, A_qw, A_qb, A_qa, A_kw, A_kb, A_ka,
                                  A_vw, A_vb, A_va, Qh, Kh, Vh);
  k_lnrow<<<8192, 256, 0, stream>>>(Qh, 520, A_qlg, A_qlb);
  k_lnrow<<<8192, 256, 0, stream>>>(Kh, 520, A_klg, A_klb);
  k_lnrow<<<8192, 256, 0, stream>>>(Vh, 2080, A_vlg, A_vlb);
  k_attn<<<8192, 256, 0, stream>>>(Qh, Kh, Vh, d_in[44], d_in[45], flagp, avb);
  k_pproj<<<2048, 256, 0, stream>>>(avb, A_pw, A_pb, A_pa, phb);
  k_lnfinal<<<2048, 256, 0, stream>>>(phb, A_plg, A_plb, inter, flagp, d_out);
}